// Round 1
// baseline (1076.692 us; speedup 1.0000x reference)
//
#include <hip/hip_runtime.h>
#include <math.h>

__device__ __forceinline__ float wave_sum(float v){
#pragma unroll
  for (int m = 1; m < 64; m <<= 1) v += __shfl_xor(v, m, 64);
  return v;
}

// ---------------- CSR build (dst-major, self-loop first per node) ----------------
__global__ void k_deg_init(int* __restrict__ deg, int n){
  int i = blockIdx.x*blockDim.x + threadIdx.x;
  if (i < n) deg[i] = 1;          // self loop
}

__global__ void k_deg_count(const int* __restrict__ dst, int* __restrict__ deg, int e){
  int i = blockIdx.x*blockDim.x + threadIdx.x;
  if (i < e) atomicAdd(&deg[dst[i]], 1);
}

__global__ void k_scan(const int* __restrict__ deg, int* __restrict__ rowptr, int n){
  __shared__ int sm[1024];
  int t = threadIdx.x;
  int chunk = (n + 1023) >> 10;
  int s0 = t*chunk, s1 = min(s0+chunk, n);
  int s = 0;
  for (int i = s0; i < s1; ++i) s += deg[i];
  sm[t] = s; __syncthreads();
  for (int off = 1; off < 1024; off <<= 1){
    int v = sm[t];
    if (t >= off) v += sm[t-off];
    __syncthreads();
    sm[t] = v;
    __syncthreads();
  }
  int base = (t == 0) ? 0 : sm[t-1];
  for (int i = s0; i < s1; ++i){ rowptr[i] = base; base += deg[i]; }
  if (t == 1023) rowptr[n] = sm[1023];
}

__global__ void k_selfloop(const int* __restrict__ rowptr, int* __restrict__ cursor,
                           int* __restrict__ csr, float* __restrict__ gc, int n){
  int i = blockIdx.x*blockDim.x + threadIdx.x;
  if (i < n){
    int r = rowptr[i];
    csr[r] = i;                   // self loop entry
    cursor[i] = r + 1;
  }
  if (i < 512) gc[i] = 0.f;       // zero the pooling accumulator
}

__global__ void k_scatter(const int* __restrict__ src, const int* __restrict__ dst,
                          int* __restrict__ cursor, int* __restrict__ csr, int e){
  int i = blockIdx.x*blockDim.x + threadIdx.x;
  if (i < e){
    int pos = atomicAdd(&cursor[dst[i]], 1);
    csr[pos] = src[i];
  }
}

// ---------------- per-layer node transforms: xl, xr, residual(+bias) ----------------
template<int K>
__global__ void k_node_transform(const float* __restrict__ h,
                                 const float* __restrict__ Wl, const float* __restrict__ bl,
                                 const float* __restrict__ Wr, const float* __restrict__ br,
                                 const float* __restrict__ Wres, const float* __restrict__ bias,
                                 float* __restrict__ xl, float* __restrict__ xr,
                                 float* __restrict__ res, int n){
  int wid  = (blockIdx.x*blockDim.x + threadIdx.x) >> 6;
  int lane = threadIdx.x & 63;
  if (wid >= n) return;
  float hv = (lane < K) ? h[(size_t)wid*K + lane] : 0.f;
  float aL = bl[lane], aR = br[lane], aS = bias[lane];
#pragma unroll 8
  for (int k = 0; k < K; ++k){
    float hk = __shfl(hv, k, 64);
    aL = fmaf(hk, Wl[k*64+lane],   aL);
    aR = fmaf(hk, Wr[k*64+lane],   aR);
    aS = fmaf(hk, Wres[k*64+lane], aS);
  }
  size_t o = (size_t)wid*64 + lane;
  xl[o] = aL; xr[o] = aR; res[o] = aS;
}

// ------- fused: edge softmax (online) + aggregate + residual + layernorm + relu -------
__global__ void k_gat_edge(const float* __restrict__ xl, const float* __restrict__ xr,
                           const float* __restrict__ att,
                           const float* __restrict__ lng, const float* __restrict__ lnb,
                           const int* __restrict__ rowptr, const int* __restrict__ csr,
                           float* __restrict__ hio /* in: residual, out: h_next */, int n){
  int node = (blockIdx.x*blockDim.x + threadIdx.x) >> 6;
  int lane = threadIdx.x & 63;
  if (node >= n) return;
  float xrv  = xr[(size_t)node*64 + lane];
  float attv = att[lane];
  float m = -INFINITY, d = 0.f, acc = 0.f;
  int p1 = rowptr[node+1];
  for (int p = rowptr[node]; p < p1; ++p){
    int s = csr[p];
    float xlv = xl[(size_t)s*64 + lane];
    float v = xlv + xrv;
    v = v > 0.f ? v : 0.2f*v;                 // leaky_relu(., 0.2)
    float logit = wave_sum(v * attv);
    float nm = fmaxf(m, logit);
    float sc = __expf(m - nm);                // 0 on first edge (m = -inf)
    float w  = __expf(logit - nm);
    d   = d*sc + w;
    acc = fmaf(acc, sc, w*xlv);
    m = nm;
  }
  size_t o = (size_t)node*64 + lane;
  float out = acc/d + hio[o];                 // + residual (h@resW + bias)
  float mean = wave_sum(out) * 0.015625f;
  float diff = out - mean;
  float var  = wave_sum(diff*diff) * 0.015625f;
  float y = diff * rsqrtf(var + 1e-5f) * lng[lane] + lnb[lane];
  hio[o] = fmaxf(y, 0.f);                     // relu(layernorm)
}

// ---------------- global add pool (batch is sorted) ----------------
__global__ void k_pool(const float* __restrict__ h, const int* __restrict__ batch,
                       float* __restrict__ gc, int n){
  int wid  = (blockIdx.x*blockDim.x + threadIdx.x) >> 6;
  int lane = threadIdx.x & 63;
  int n0 = wid*64;
  if (n0 >= n) return;
  int n1 = min(n0+64, n);
  int curg = batch[n0];
  float s = 0.f;
  for (int i = n0; i < n1; ++i){
    int g = batch[i];
    if (g != curg){ atomicAdd(&gc[curg*64+lane], s); s = 0.f; curg = g; }
    s += h[(size_t)i*64 + lane];
  }
  atomicAdd(&gc[curg*64+lane], s);
}

// ---------------- G[g] = gc[g] @ W1c + b1 ----------------
__global__ void k_graph_proj(const float* __restrict__ gc, const float* __restrict__ W1,
                             const float* __restrict__ b1, float* __restrict__ G){
  int g = threadIdx.x >> 7;       // 8 graphs x 128 cols = 1024 threads
  int j = threadIdx.x & 127;
  float a = b1[j];
#pragma unroll 8
  for (int k = 0; k < 64; ++k) a = fmaf(gc[g*64+k], W1[(128+k)*128 + j], a);
  G[g*128 + j] = a;
}

// ---------------- A = nr @ W1a ; B = nr @ W1b ----------------
__global__ void k_node_proj(const float* __restrict__ nr, const float* __restrict__ W1,
                            float* __restrict__ A, float* __restrict__ B, int n){
  int wid  = (blockIdx.x*blockDim.x + threadIdx.x) >> 6;
  int lane = threadIdx.x & 63;
  if (wid >= n) return;
  float hv = nr[(size_t)wid*64 + lane];
  float a0=0.f, a1=0.f, b0=0.f, b1=0.f;
#pragma unroll 8
  for (int k = 0; k < 64; ++k){
    float hk = __shfl(hv, k, 64);
    a0 = fmaf(hk, W1[k*128 + lane],          a0);
    a1 = fmaf(hk, W1[k*128 + lane + 64],     a1);
    b0 = fmaf(hk, W1[(64+k)*128 + lane],     b0);
    b1 = fmaf(hk, W1[(64+k)*128 + lane + 64],b1);
  }
  size_t o = (size_t)wid*128 + lane;
  A[o] = a0; A[o+64] = a1; B[o] = b0; B[o+64] = b1;
}

// ---------------- final per-edge MLP: relu(A[s]+B[d]+G[g]) . W2 + b2 ----------------
__global__ void k_edge_out(const float* __restrict__ A, const float* __restrict__ B,
                           const float* __restrict__ G,
                           const int* __restrict__ src, const int* __restrict__ dst,
                           const int* __restrict__ batch,
                           const float* __restrict__ W2, const float* __restrict__ b2,
                           float* __restrict__ out, int e){
  int eid  = (blockIdx.x*blockDim.x + threadIdx.x) >> 6;
  int lane = threadIdx.x & 63;
  if (eid >= e) return;
  int s = src[eid], d = dst[eid];
  int g = batch[s];
  size_t so = (size_t)s*128 + lane, dofs = (size_t)d*128 + lane;
  float h0 = A[so]    + B[dofs]    + G[g*128 + lane];
  float h1 = A[so+64] + B[dofs+64] + G[g*128 + lane + 64];
  h0 = fmaxf(h0, 0.f); h1 = fmaxf(h1, 0.f);
  float part = fmaf(h0, W2[lane], h1*W2[lane+64]);
  float sum = wave_sum(part);
  if (lane == 0) out[eid] = sum + b2[0];
}

extern "C" void kernel_launch(void* const* d_in, const int* in_sizes, int n_in,
                              void* d_out, int out_size, void* d_ws, size_t ws_size,
                              hipStream_t stream){
  const float* x     = (const float*)d_in[0];
  const int*   ei    = (const int*)d_in[1];
  const int*   batch = (const int*)d_in[2];
  const int N = in_sizes[2];
  const int E = in_sizes[1] / 2;
  const int* src = ei;
  const int* dst = ei + E;

  float* ws = (float*)d_ws;
  const size_t N64 = (size_t)N * 64;
  // layout: [xl][xr][hE][buf5][hD] then ints, then gc/G
  float* xl   = ws;
  float* xr   = ws + N64;
  float* hE   = ws + 2*N64;
  /* buf5 = ws + 3*N64 (second half of B) */
  float* hD   = ws + 4*N64;
  float* Amat = xl;                 // N x 128 (xl+xr contiguous)
  float* Bmat = hE;                 // N x 128 (hE+buf5 contiguous)
  int* rowptr = (int*)(ws + 5*N64); // N+1
  int* cursor = rowptr + (N + 1);   // N (also used as deg before scan)
  int* csr    = cursor + N;         // N + E
  float* gc   = (float*)(csr + (N + E)); // 8*64
  float* G    = gc + 512;                // 8*128

  // ---- CSR build (once, reused by all 3 layers) ----
  k_deg_init <<<(N+255)/256, 256, 0, stream>>>(cursor, N);
  k_deg_count<<<(E+255)/256, 256, 0, stream>>>(dst, cursor, E);
  k_scan     <<<1, 1024, 0, stream>>>(cursor, rowptr, N);
  k_selfloop <<<(N+255)/256, 256, 0, stream>>>(rowptr, cursor, csr, gc, N);
  k_scatter  <<<(E+255)/256, 256, 0, stream>>>(src, dst, cursor, csr, E);

  // ---- 3 GATv2 layers ----
  const float* h = x;
  float* hn = hD;
  for (int l = 0; l < 3; ++l){
    const float* Wl   = (const float*)d_in[3 + 9*l + 0];
    const float* bl   = (const float*)d_in[3 + 9*l + 1];
    const float* Wr   = (const float*)d_in[3 + 9*l + 2];
    const float* br   = (const float*)d_in[3 + 9*l + 3];
    const float* att  = (const float*)d_in[3 + 9*l + 4];
    const float* Wres = (const float*)d_in[3 + 9*l + 5];
    const float* bias = (const float*)d_in[3 + 9*l + 6];
    const float* lng  = (const float*)d_in[3 + 9*l + 7];
    const float* lnb  = (const float*)d_in[3 + 9*l + 8];
    if (l == 0)
      k_node_transform<32><<<(N+3)/4, 256, 0, stream>>>(h, Wl, bl, Wr, br, Wres, bias, xl, xr, hn, N);
    else
      k_node_transform<64><<<(N+3)/4, 256, 0, stream>>>(h, Wl, bl, Wr, br, Wres, bias, xl, xr, hn, N);
    k_gat_edge<<<(N+3)/4, 256, 0, stream>>>(xl, xr, att, lng, lnb, rowptr, csr, hn, N);
    h = hn;
    hn = (l == 0) ? hE : hD;   // L0->hD, L1->hE, L2->hD ; final node_repr = hD
  }

  // ---- readout ----
  const float* W1 = (const float*)d_in[30];
  const float* b1 = (const float*)d_in[31];
  const float* W2 = (const float*)d_in[32];
  const float* b2 = (const float*)d_in[33];

  int pool_waves = (N + 63) / 64;
  k_pool      <<<(pool_waves+3)/4, 256, 0, stream>>>(hD, batch, gc, N);
  k_graph_proj<<<1, 1024, 0, stream>>>(gc, W1, b1, G);
  k_node_proj <<<(N+3)/4, 256, 0, stream>>>(hD, W1, Amat, Bmat, N);
  k_edge_out  <<<(E+3)/4, 256, 0, stream>>>(Amat, Bmat, G, src, dst, batch, W2, b2,
                                            (float*)d_out, E);
}

// Round 2
// 830.323 us; speedup vs baseline: 1.2967x; 1.2967x over previous
//
#include <hip/hip_runtime.h>
#include <math.h>

__device__ __forceinline__ float wave_sum(float v){
#pragma unroll
  for (int m = 1; m < 64; m <<= 1) v += __shfl_xor(v, m, 64);
  return v;
}

__device__ __forceinline__ unsigned pack_bf16(float a, float b){
  unsigned ua = __float_as_uint(a), ub = __float_as_uint(b);
  ua = (ua + 0x7FFFu + ((ua >> 16) & 1u)) >> 16;
  ub = (ub + 0x7FFFu + ((ub >> 16) & 1u)) >> 16;
  return ua | (ub << 16);
}
__device__ __forceinline__ float2 unpack_bf16(unsigned p){
  float2 r;
  r.x = __uint_as_float(p << 16);
  r.y = __uint_as_float(p & 0xFFFF0000u);
  return r;
}

// ---------------- CSR build (dst-major, self-loop first per node) ----------------
__global__ void k_deg_init(int* __restrict__ deg, int n){
  int i = blockIdx.x*blockDim.x + threadIdx.x;
  if (i < n) deg[i] = 1;          // self loop
}

__global__ void k_deg_count(const int* __restrict__ dst, int* __restrict__ deg, int e){
  int i = blockIdx.x*blockDim.x + threadIdx.x;
  if (i < e) atomicAdd(&deg[dst[i]], 1);
}

__global__ void k_scan(const int* __restrict__ deg, int* __restrict__ rowptr, int n){
  __shared__ int sm[1024];
  int t = threadIdx.x;
  int chunk = (n + 1023) >> 10;
  int s0 = t*chunk, s1 = min(s0+chunk, n);
  int s = 0;
  for (int i = s0; i < s1; ++i) s += deg[i];
  sm[t] = s; __syncthreads();
  for (int off = 1; off < 1024; off <<= 1){
    int v = sm[t];
    if (t >= off) v += sm[t-off];
    __syncthreads();
    sm[t] = v;
    __syncthreads();
  }
  int base = (t == 0) ? 0 : sm[t-1];
  for (int i = s0; i < s1; ++i){ rowptr[i] = base; base += deg[i]; }
  if (t == 1023) rowptr[n] = sm[1023];
}

__global__ void k_selfloop(const int* __restrict__ rowptr, int* __restrict__ cursor,
                           int* __restrict__ csr, float* __restrict__ gc, int n){
  int i = blockIdx.x*blockDim.x + threadIdx.x;
  if (i < n){
    int r = rowptr[i];
    csr[r] = i;                   // self loop entry
    cursor[i] = r + 1;
  }
  if (i < 512) gc[i] = 0.f;       // zero the pooling accumulator
}

__global__ void k_scatter(const int* __restrict__ src, const int* __restrict__ dst,
                          int* __restrict__ cursor, int* __restrict__ csr, int e){
  int i = blockIdx.x*blockDim.x + threadIdx.x;
  if (i < e){
    int pos = atomicAdd(&cursor[dst[i]], 1);
    csr[pos] = src[i];
  }
}

// ------- per-layer node transforms: xl, xr, residual(+bias); 4 nodes per wave -------
template<int K>
__global__ void k_node_transform(const float* __restrict__ h,
                                 const float* __restrict__ Wl, const float* __restrict__ bl,
                                 const float* __restrict__ Wr, const float* __restrict__ br,
                                 const float* __restrict__ Wres, const float* __restrict__ bias,
                                 float* __restrict__ xl, float* __restrict__ xr,
                                 float* __restrict__ res, int n){
  int wq   = (blockIdx.x*blockDim.x + threadIdx.x) >> 6;
  int lane = threadIdx.x & 63;
  int n0 = wq * 4;
  if (n0 >= n) return;
  float hv[4];
#pragma unroll
  for (int j = 0; j < 4; ++j){
    int node = min(n0 + j, n - 1);
    hv[j] = (lane < K) ? h[(size_t)node*K + lane] : 0.f;
  }
  float aL[4], aR[4], aS[4];
  float blv = bl[lane], brv = br[lane], bsv = bias[lane];
#pragma unroll
  for (int j = 0; j < 4; ++j){ aL[j] = blv; aR[j] = brv; aS[j] = bsv; }
#pragma unroll 4
  for (int k = 0; k < K; ++k){
    float wl = Wl[k*64+lane], wr = Wr[k*64+lane], wsv = Wres[k*64+lane];
#pragma unroll
    for (int j = 0; j < 4; ++j){
      float hk = __shfl(hv[j], k, 64);
      aL[j] = fmaf(hk, wl,  aL[j]);
      aR[j] = fmaf(hk, wr,  aR[j]);
      aS[j] = fmaf(hk, wsv, aS[j]);
    }
  }
#pragma unroll
  for (int j = 0; j < 4; ++j){
    int node = n0 + j;
    if (node < n){
      size_t o = (size_t)node*64 + lane;
      xl[o] = aL[j]; xr[o] = aR[j]; res[o] = aS[j];
    }
  }
}

// ------- fused: edge softmax (online, 2 edges in flight) + aggregate + LN + relu -------
__global__ void k_gat_edge(const float* __restrict__ xl, const float* __restrict__ xr,
                           const float* __restrict__ att,
                           const float* __restrict__ lng, const float* __restrict__ lnb,
                           const int* __restrict__ rowptr, const int* __restrict__ csr,
                           float* __restrict__ hio /* in: residual, out: h_next */, int n){
  int node = (blockIdx.x*blockDim.x + threadIdx.x) >> 6;
  int lane = threadIdx.x & 63;
  if (node >= n) return;
  int half = lane >> 5;          // edge slot (0/1)
  int c    = lane & 31;          // channel pair: channels 2c, 2c+1
  size_t base = (size_t)node*64 + 2*c;
  float2 xrv  = *(const float2*)&xr[base];
  float2 attv = *(const float2*)&att[2*c];
  float m = -1e30f, dsum = 0.f;
  float accx = 0.f, accy = 0.f;
  int p0 = rowptr[node], p1 = rowptr[node+1];
  int rounds = (p1 - p0 + 1) >> 1;
  for (int r = 0; r < rounds; ++r){
    int p = p0 + 2*r + half;
    bool valid = p < p1;
    int s = csr[valid ? p : p0];
    float2 xlv = *(const float2*)&xl[(size_t)s*64 + 2*c];
    float vx = xlv.x + xrv.x, vy = xlv.y + xrv.y;
    vx = vx > 0.f ? vx : 0.2f*vx;
    vy = vy > 0.f ? vy : 0.2f*vy;
    float partial = fmaf(vx, attv.x, vy*attv.y);
#pragma unroll
    for (int mm = 1; mm < 32; mm <<= 1) partial += __shfl_xor(partial, mm, 64);
    float logit = valid ? partial : -3e30f;
    float nm = fmaxf(m, logit);
    float sc = __expf(m - nm);
    float w  = __expf(logit - nm);
    dsum = fmaf(dsum, sc, w);
    accx = fmaf(accx, sc, w*xlv.x);
    accy = fmaf(accy, sc, w*xlv.y);
    m = nm;
  }
  // merge the two halves' online-softmax states
  float mo = __shfl_xor(m, 32, 64);
  float M  = fmaxf(m, mo);
  float myScale = __expf(m - M);
  float dsc = dsum * myScale;
  float dtot = dsc + __shfl_xor(dsc, 32, 64);
  float ax = accx * myScale, ay = accy * myScale;
  ax += __shfl_xor(ax, 32, 64);
  ay += __shfl_xor(ay, 32, 64);
  float2 resv = *(const float2*)&hio[base];
  float ox = ax/dtot + resv.x;
  float oy = ay/dtot + resv.y;
  // layernorm over 64 channels (each channel counted twice across the wave)
  float mean = wave_sum(ox + oy) * 0.5f * 0.015625f;
  float dx = ox - mean, dy = oy - mean;
  float var = wave_sum(fmaf(dx, dx, dy*dy)) * 0.5f * 0.015625f;
  float rstd = rsqrtf(var + 1e-5f);
  float2 lg = *(const float2*)&lng[2*c];
  float2 lb = *(const float2*)&lnb[2*c];
  if (half == 0){
    float2 out;
    out.x = fmaxf(fmaf(dx*rstd, lg.x, lb.x), 0.f);
    out.y = fmaxf(fmaf(dy*rstd, lg.y, lb.y), 0.f);
    *(float2*)&hio[base] = out;
  }
}

// ---------------- global add pool (batch is sorted) ----------------
__global__ void k_pool(const float* __restrict__ h, const int* __restrict__ batch,
                       float* __restrict__ gc, int n){
  int wid  = (blockIdx.x*blockDim.x + threadIdx.x) >> 6;
  int lane = threadIdx.x & 63;
  int n0 = wid*64;
  if (n0 >= n) return;
  int n1 = min(n0+64, n);
  int curg = batch[n0];
  float s = 0.f;
  for (int i = n0; i < n1; ++i){
    int g = batch[i];
    if (g != curg){ atomicAdd(&gc[curg*64+lane], s); s = 0.f; curg = g; }
    s += h[(size_t)i*64 + lane];
  }
  atomicAdd(&gc[curg*64+lane], s);
}

// ---------------- G[g] = gc[g] @ W1c + b1 ----------------
__global__ void k_graph_proj(const float* __restrict__ gc, const float* __restrict__ W1,
                             const float* __restrict__ b1, float* __restrict__ G){
  int g = threadIdx.x >> 7;       // 8 graphs x 128 cols = 1024 threads
  int j = threadIdx.x & 127;
  float a = b1[j];
#pragma unroll 8
  for (int k = 0; k < 64; ++k) a = fmaf(gc[g*64+k], W1[(128+k)*128 + j], a);
  G[g*128 + j] = a;
}

// -------- A = nr @ W1a ; B = nr @ W1b (bf16 packed, 4 nodes per wave) --------
// lane holds output columns (2*lane, 2*lane+1)
__global__ void k_node_proj(const float* __restrict__ nr, const float* __restrict__ W1,
                            unsigned* __restrict__ Au, unsigned* __restrict__ Bu, int n){
  int wq   = (blockIdx.x*blockDim.x + threadIdx.x) >> 6;
  int lane = threadIdx.x & 63;
  int n0 = wq * 4;
  if (n0 >= n) return;
  float hv[4];
#pragma unroll
  for (int j = 0; j < 4; ++j){
    int node = min(n0 + j, n - 1);
    hv[j] = nr[(size_t)node*64 + lane];
  }
  float a0[4] = {0,0,0,0}, a1[4] = {0,0,0,0}, b0[4] = {0,0,0,0}, b1v[4] = {0,0,0,0};
#pragma unroll 4
  for (int k = 0; k < 64; ++k){
    float2 wa = *(const float2*)&W1[k*128 + 2*lane];
    float2 wb = *(const float2*)&W1[(64+k)*128 + 2*lane];
#pragma unroll
    for (int j = 0; j < 4; ++j){
      float hk = __shfl(hv[j], k, 64);
      a0[j]  = fmaf(hk, wa.x, a0[j]);
      a1[j]  = fmaf(hk, wa.y, a1[j]);
      b0[j]  = fmaf(hk, wb.x, b0[j]);
      b1v[j] = fmaf(hk, wb.y, b1v[j]);
    }
  }
#pragma unroll
  for (int j = 0; j < 4; ++j){
    int node = n0 + j;
    if (node < n){
      size_t o = (size_t)node*64 + lane;
      Au[o] = pack_bf16(a0[j], a1[j]);
      Bu[o] = pack_bf16(b0[j], b1v[j]);
    }
  }
}

// -------- final per-edge MLP: relu(A[s]+B[d]+G[g]) . W2 + b2  (A/B bf16) --------
__global__ void k_edge_out(const unsigned* __restrict__ Au, const unsigned* __restrict__ Bu,
                           const float* __restrict__ G,
                           const int* __restrict__ src, const int* __restrict__ dst,
                           const int* __restrict__ batch,
                           const float* __restrict__ W2, const float* __restrict__ b2,
                           float* __restrict__ out, int e){
  int eid  = (blockIdx.x*blockDim.x + threadIdx.x) >> 6;
  int lane = threadIdx.x & 63;
  if (eid >= e) return;
  int s = src[eid], d = dst[eid];
  int g = batch[s];
  float2 a = unpack_bf16(Au[(size_t)s*64 + lane]);
  float2 b = unpack_bf16(Bu[(size_t)d*64 + lane]);
  float2 gv = *(const float2*)&G[g*128 + 2*lane];
  float2 w2 = *(const float2*)&W2[2*lane];
  float h0 = fmaxf(a.x + b.x + gv.x, 0.f);
  float h1 = fmaxf(a.y + b.y + gv.y, 0.f);
  float part = fmaf(h0, w2.x, h1*w2.y);
  float sum = wave_sum(part);
  if (lane == 0) out[eid] = sum + b2[0];
}

extern "C" void kernel_launch(void* const* d_in, const int* in_sizes, int n_in,
                              void* d_out, int out_size, void* d_ws, size_t ws_size,
                              hipStream_t stream){
  const float* x     = (const float*)d_in[0];
  const int*   ei    = (const int*)d_in[1];
  const int*   batch = (const int*)d_in[2];
  const int N = in_sizes[2];
  const int E = in_sizes[1] / 2;
  const int* src = ei;
  const int* dst = ei + E;

  float* ws = (float*)d_ws;
  const size_t N64 = (size_t)N * 64;
  // layout: [xl][xr][hE][buf5][hD] then ints (even-padded), then gc/G
  float* xl   = ws;
  float* xr   = ws + N64;
  float* hE   = ws + 2*N64;
  float* hD   = ws + 4*N64;
  unsigned* Au = (unsigned*)xl;      // N x 64 packed bf16x2
  unsigned* Bu = (unsigned*)xr;
  int* rowptr = (int*)(ws + 5*N64);  // N+2 (padded even)
  int* cursor = rowptr + (N + 2);    // N (also deg before scan)
  int* csr    = cursor + N;          // N + E
  float* gc   = (float*)(csr + (N + E)); // 8*64 (8B aligned: 3N+2+E even)
  float* G    = gc + 512;                // 8*128

  // ---- CSR build (once, reused by all 3 layers) ----
  k_deg_init <<<(N+255)/256, 256, 0, stream>>>(cursor, N);
  k_deg_count<<<(E+255)/256, 256, 0, stream>>>(dst, cursor, E);
  k_scan     <<<1, 1024, 0, stream>>>(cursor, rowptr, N);
  k_selfloop <<<(N+255)/256, 256, 0, stream>>>(rowptr, cursor, csr, gc, N);
  k_scatter  <<<(E+255)/256, 256, 0, stream>>>(src, dst, cursor, csr, E);

  // ---- 3 GATv2 layers ----
  const float* h = x;
  float* hn = hD;
  for (int l = 0; l < 3; ++l){
    const float* Wl   = (const float*)d_in[3 + 9*l + 0];
    const float* bl   = (const float*)d_in[3 + 9*l + 1];
    const float* Wr   = (const float*)d_in[3 + 9*l + 2];
    const float* br   = (const float*)d_in[3 + 9*l + 3];
    const float* att  = (const float*)d_in[3 + 9*l + 4];
    const float* Wres = (const float*)d_in[3 + 9*l + 5];
    const float* bias = (const float*)d_in[3 + 9*l + 6];
    const float* lng  = (const float*)d_in[3 + 9*l + 7];
    const float* lnb  = (const float*)d_in[3 + 9*l + 8];
    if (l == 0)
      k_node_transform<32><<<(N+15)/16, 256, 0, stream>>>(h, Wl, bl, Wr, br, Wres, bias, xl, xr, hn, N);
    else
      k_node_transform<64><<<(N+15)/16, 256, 0, stream>>>(h, Wl, bl, Wr, br, Wres, bias, xl, xr, hn, N);
    k_gat_edge<<<(N+3)/4, 256, 0, stream>>>(xl, xr, att, lng, lnb, rowptr, csr, hn, N);
    h = hn;
    hn = (l == 0) ? hE : hD;   // L0->hD, L1->hE, L2->hD ; final node_repr = hD
  }

  // ---- readout ----
  const float* W1 = (const float*)d_in[30];
  const float* b1 = (const float*)d_in[31];
  const float* W2 = (const float*)d_in[32];
  const float* b2 = (const float*)d_in[33];

  int pool_waves = (N + 63) / 64;
  k_pool      <<<(pool_waves+3)/4, 256, 0, stream>>>(hD, batch, gc, N);
  k_graph_proj<<<1, 1024, 0, stream>>>(gc, W1, b1, G);
  k_node_proj <<<(N+15)/16, 256, 0, stream>>>(hD, W1, Au, Bu, N);
  k_edge_out  <<<(E+3)/4, 256, 0, stream>>>(Au, Bu, G, src, dst, batch, W2, b2,
                                            (float*)d_out, E);
}

// Round 3
// 653.265 us; speedup vs baseline: 1.6482x; 1.2710x over previous
//
#include <hip/hip_runtime.h>
#include <math.h>

__device__ __forceinline__ float wave_sum(float v){
#pragma unroll
  for (int m = 1; m < 64; m <<= 1) v += __shfl_xor(v, m, 64);
  return v;
}

__device__ __forceinline__ unsigned pack_bf16(float a, float b){
  unsigned ua = __float_as_uint(a), ub = __float_as_uint(b);
  ua = (ua + 0x7FFFu + ((ua >> 16) & 1u)) >> 16;
  ub = (ub + 0x7FFFu + ((ub >> 16) & 1u)) >> 16;
  return ua | (ub << 16);
}
__device__ __forceinline__ float2 unpack_bf16(unsigned p){
  float2 r;
  r.x = __uint_as_float(p << 16);
  r.y = __uint_as_float(p & 0xFFFF0000u);
  return r;
}

// ---------------- CSR build (dst-major, self-loop first per node) ----------------
__global__ void k_deg_init(int* __restrict__ deg, int n){
  int i = blockIdx.x*blockDim.x + threadIdx.x;
  if (i < n) deg[i] = 1;          // self loop
}

__global__ void k_deg_count(const int* __restrict__ dst, int* __restrict__ deg, int e){
  int i = blockIdx.x*blockDim.x + threadIdx.x;
  if (i < e) atomicAdd(&deg[dst[i]], 1);
}

__global__ void k_scan(const int* __restrict__ deg, int* __restrict__ rowptr, int n){
  __shared__ int sm[1024];
  int t = threadIdx.x;
  int chunk = (n + 1023) >> 10;
  int s0 = t*chunk, s1 = min(s0+chunk, n);
  int s = 0;
  for (int i = s0; i < s1; ++i) s += deg[i];
  sm[t] = s; __syncthreads();
  for (int off = 1; off < 1024; off <<= 1){
    int v = sm[t];
    if (t >= off) v += sm[t-off];
    __syncthreads();
    sm[t] = v;
    __syncthreads();
  }
  int base = (t == 0) ? 0 : sm[t-1];
  for (int i = s0; i < s1; ++i){ rowptr[i] = base; base += deg[i]; }
  if (t == 1023) rowptr[n] = sm[1023];
}

__global__ void k_selfloop(const int* __restrict__ rowptr, int* __restrict__ cursor,
                           int* __restrict__ csr, float* __restrict__ gc, int n){
  int i = blockIdx.x*blockDim.x + threadIdx.x;
  if (i < n){
    int r = rowptr[i];
    csr[r] = i;                   // self loop entry
    cursor[i] = r + 1;
  }
  if (i < 512) gc[i] = 0.f;       // zero the pooling accumulator
}

__global__ void k_scatter(const int* __restrict__ src, const int* __restrict__ dst,
                          int* __restrict__ cursor, int* __restrict__ csr, int e){
  int i = blockIdx.x*blockDim.x + threadIdx.x;
  if (i < e){
    int pos = atomicAdd(&cursor[dst[i]], 1);
    csr[pos] = src[i];
  }
}

// ------- per-layer node transforms: xl, xr, residual(+bias); 8 nodes per wave -------
template<int K>
__global__ void k_node_transform(const float* __restrict__ h,
                                 const float* __restrict__ Wl, const float* __restrict__ bl,
                                 const float* __restrict__ Wr, const float* __restrict__ br,
                                 const float* __restrict__ Wres, const float* __restrict__ bias,
                                 float* __restrict__ xl, float* __restrict__ xr,
                                 float* __restrict__ res, int n){
  int wq   = (blockIdx.x*blockDim.x + threadIdx.x) >> 6;
  int lane = threadIdx.x & 63;
  int n0 = wq * 8;
  if (n0 >= n) return;
  float hv[8];
#pragma unroll
  for (int j = 0; j < 8; ++j){
    int node = min(n0 + j, n - 1);
    hv[j] = (lane < K) ? h[(size_t)node*K + lane] : 0.f;
  }
  float aL[8], aR[8], aS[8];
  float blv = bl[lane], brv = br[lane], bsv = bias[lane];
#pragma unroll
  for (int j = 0; j < 8; ++j){ aL[j] = blv; aR[j] = brv; aS[j] = bsv; }
#pragma unroll 4
  for (int k = 0; k < K; ++k){
    float wl = Wl[k*64+lane], wr = Wr[k*64+lane], wsv = Wres[k*64+lane];
#pragma unroll
    for (int j = 0; j < 8; ++j){
      float hk = __shfl(hv[j], k, 64);
      aL[j] = fmaf(hk, wl,  aL[j]);
      aR[j] = fmaf(hk, wr,  aR[j]);
      aS[j] = fmaf(hk, wsv, aS[j]);
    }
  }
#pragma unroll
  for (int j = 0; j < 8; ++j){
    int node = n0 + j;
    if (node < n){
      size_t o = (size_t)node*64 + lane;
      xl[o] = aL[j]; xr[o] = aR[j]; res[o] = aS[j];
    }
  }
}

// --- fused: edge softmax (online, 4 edges in flight, pipelined gathers) + LN + relu ---
__global__ void k_gat_edge(const float* __restrict__ xl, const float* __restrict__ xr,
                           const float* __restrict__ att,
                           const float* __restrict__ lng, const float* __restrict__ lnb,
                           const int* __restrict__ rowptr, const int* __restrict__ csr,
                           float* __restrict__ hio /* in: residual, out: h_next */, int n){
  int node = (blockIdx.x*blockDim.x + threadIdx.x) >> 6;
  int lane = threadIdx.x & 63;
  if (node >= n) return;
  int sub = lane >> 4;          // edge slot (0..3)
  int l   = lane & 15;          // channels 4l .. 4l+3
  size_t base = (size_t)node*64 + 4*l;
  float4 xrv  = *(const float4*)&xr[base];
  float4 attv = *(const float4*)&att[4*l];
  int p0 = rowptr[node], p1 = rowptr[node+1];
  int deg = p1 - p0;            // >= 1 (self loop)
  int sreg = csr[p0 + min(lane, deg-1)];   // cache first 64 neighbor ids in regs
  int rounds = (deg + 3) >> 2;
  float m = -1e30f, dsum = 0.f;
  float a0=0.f, a1=0.f, a2=0.f, a3=0.f;
  // stage 0 prefetch
  int e = sub;
  bool vcur = e < deg;
  int scur = __shfl(sreg, vcur ? e : 0, 64);
  float4 xcur = *(const float4*)&xl[(size_t)scur*64 + 4*l];
  for (int r = 0; r < rounds; ++r){
    // prefetch next round's rows (independent of this round's compute)
    int en = 4*(r+1) + sub;
    bool vn = en < deg;
    int sn;
    if (en < 64) sn = __shfl(sreg, vn ? en : 0, 64);
    else         sn = csr[p0 + (vn ? en : 0)];
    float4 xnxt = xcur;
    if (r + 1 < rounds) xnxt = *(const float4*)&xl[(size_t)sn*64 + 4*l];
    // compute current
    float vx = xcur.x + xrv.x, vy = xcur.y + xrv.y;
    float vz = xcur.z + xrv.z, vw = xcur.w + xrv.w;
    vx = vx > 0.f ? vx : 0.2f*vx;  vy = vy > 0.f ? vy : 0.2f*vy;
    vz = vz > 0.f ? vz : 0.2f*vz;  vw = vw > 0.f ? vw : 0.2f*vw;
    float partial = fmaf(vx, attv.x, fmaf(vy, attv.y, fmaf(vz, attv.z, vw*attv.w)));
#pragma unroll
    for (int mm = 1; mm < 16; mm <<= 1) partial += __shfl_xor(partial, mm, 64);
    float logit = vcur ? partial : -3e30f;
    float nm = fmaxf(m, logit);
    float sc = __expf(m - nm);
    float w  = __expf(logit - nm);
    dsum = fmaf(dsum, sc, w);
    a0 = fmaf(a0, sc, w*xcur.x);
    a1 = fmaf(a1, sc, w*xcur.y);
    a2 = fmaf(a2, sc, w*xcur.z);
    a3 = fmaf(a3, sc, w*xcur.w);
    m = nm;
    xcur = xnxt; vcur = vn;
  }
  // merge the 4 sub-groups' online-softmax states (xor 16, then xor 32)
#pragma unroll
  for (int off = 16; off < 64; off <<= 1){
    float mo = __shfl_xor(m, off, 64);
    float M  = fmaxf(m, mo);
    float sc = __expf(m - M);
    dsum *= sc; a0 *= sc; a1 *= sc; a2 *= sc; a3 *= sc;
    m = M;
    dsum += __shfl_xor(dsum, off, 64);
    a0 += __shfl_xor(a0, off, 64);
    a1 += __shfl_xor(a1, off, 64);
    a2 += __shfl_xor(a2, off, 64);
    a3 += __shfl_xor(a3, off, 64);
  }
  float4 resv = *(const float4*)&hio[base];
  float inv = 1.f / dsum;
  float ox = fmaf(a0, inv, resv.x);
  float oy = fmaf(a1, inv, resv.y);
  float oz = fmaf(a2, inv, resv.z);
  float ow = fmaf(a3, inv, resv.w);
  // layernorm over 64 channels; each channel appears 4x across the wave
  float mean = wave_sum(ox + oy + oz + ow) * (1.f/256.f);
  float dx = ox - mean, dy = oy - mean, dz = oz - mean, dw = ow - mean;
  float var = wave_sum(fmaf(dx,dx, fmaf(dy,dy, fmaf(dz,dz, dw*dw)))) * (1.f/256.f);
  float rstd = rsqrtf(var + 1e-5f);
  if (sub == 0){
    float4 lg = *(const float4*)&lng[4*l];
    float4 lb = *(const float4*)&lnb[4*l];
    float4 out;
    out.x = fmaxf(fmaf(dx*rstd, lg.x, lb.x), 0.f);
    out.y = fmaxf(fmaf(dy*rstd, lg.y, lb.y), 0.f);
    out.z = fmaxf(fmaf(dz*rstd, lg.z, lb.z), 0.f);
    out.w = fmaxf(fmaf(dw*rstd, lg.w, lb.w), 0.f);
    *(float4*)&hio[base] = out;
  }
}

// ---------------- global add pool (batch is sorted) ----------------
__global__ void k_pool(const float* __restrict__ h, const int* __restrict__ batch,
                       float* __restrict__ gc, int n){
  int wid  = (blockIdx.x*blockDim.x + threadIdx.x) >> 6;
  int lane = threadIdx.x & 63;
  int n0 = wid*64;
  if (n0 >= n) return;
  int n1 = min(n0+64, n);
  int curg = batch[n0];
  float s = 0.f;
  for (int i = n0; i < n1; ++i){
    int g = batch[i];
    if (g != curg){ atomicAdd(&gc[curg*64+lane], s); s = 0.f; curg = g; }
    s += h[(size_t)i*64 + lane];
  }
  atomicAdd(&gc[curg*64+lane], s);
}

// ---------------- G[g] = gc[g] @ W1c + b1 ----------------
__global__ void k_graph_proj(const float* __restrict__ gc, const float* __restrict__ W1,
                             const float* __restrict__ b1, float* __restrict__ G){
  int g = threadIdx.x >> 7;       // 8 graphs x 128 cols = 1024 threads
  int j = threadIdx.x & 127;
  float a = b1[j];
#pragma unroll 8
  for (int k = 0; k < 64; ++k) a = fmaf(gc[g*64+k], W1[(128+k)*128 + j], a);
  G[g*128 + j] = a;
}

// -------- A = nr @ W1a ; B = nr @ W1b (bf16 packed, 8 nodes per wave) --------
// lane holds output columns (2*lane, 2*lane+1)
__global__ void k_node_proj(const float* __restrict__ nr, const float* __restrict__ W1,
                            unsigned* __restrict__ Au, unsigned* __restrict__ Bu, int n){
  int wq   = (blockIdx.x*blockDim.x + threadIdx.x) >> 6;
  int lane = threadIdx.x & 63;
  int n0 = wq * 8;
  if (n0 >= n) return;
  float hv[8];
#pragma unroll
  for (int j = 0; j < 8; ++j){
    int node = min(n0 + j, n - 1);
    hv[j] = nr[(size_t)node*64 + lane];
  }
  float a0[8], a1[8], b0[8], b1v[8];
#pragma unroll
  for (int j = 0; j < 8; ++j){ a0[j]=0.f; a1[j]=0.f; b0[j]=0.f; b1v[j]=0.f; }
#pragma unroll 4
  for (int k = 0; k < 64; ++k){
    float2 wa = *(const float2*)&W1[k*128 + 2*lane];
    float2 wb = *(const float2*)&W1[(64+k)*128 + 2*lane];
#pragma unroll
    for (int j = 0; j < 8; ++j){
      float hk = __shfl(hv[j], k, 64);
      a0[j]  = fmaf(hk, wa.x, a0[j]);
      a1[j]  = fmaf(hk, wa.y, a1[j]);
      b0[j]  = fmaf(hk, wb.x, b0[j]);
      b1v[j] = fmaf(hk, wb.y, b1v[j]);
    }
  }
#pragma unroll
  for (int j = 0; j < 8; ++j){
    int node = n0 + j;
    if (node < n){
      size_t o = (size_t)node*64 + lane;
      Au[o] = pack_bf16(a0[j], a1[j]);
      Bu[o] = pack_bf16(b0[j], b1v[j]);
    }
  }
}

// -- final per-edge MLP: relu(A[s]+B[d]+G[g]) . W2 + b2 ; 4 edges/wave, 16 lanes/edge --
__global__ void k_edge_out(const uint4* __restrict__ Au4, const uint4* __restrict__ Bu4,
                           const float* __restrict__ G,
                           const int* __restrict__ src, const int* __restrict__ dst,
                           const int* __restrict__ batch,
                           const float* __restrict__ W2, const float* __restrict__ b2,
                           float* __restrict__ out, int e){
  int t = blockIdx.x*blockDim.x + threadIdx.x;
  int eid = t >> 4;
  int l   = t & 15;             // channels 8l .. 8l+7
  if (eid >= e) return;
  int s = src[eid], d = dst[eid];
  int g = batch[s];
  uint4 a = Au4[(size_t)s*16 + l];
  uint4 b = Bu4[(size_t)d*16 + l];
  const float* Gp = &G[g*128 + 8*l];
  float4 g0 = *(const float4*)Gp;
  float4 g1 = *(const float4*)(Gp + 4);
  float4 w0 = *(const float4*)&W2[8*l];
  float4 w1 = *(const float4*)&W2[8*l + 4];
  float2 ax = unpack_bf16(a.x), bx = unpack_bf16(b.x);
  float2 ay = unpack_bf16(a.y), by = unpack_bf16(b.y);
  float2 az = unpack_bf16(a.z), bz = unpack_bf16(b.z);
  float2 aw = unpack_bf16(a.w), bw = unpack_bf16(b.w);
  float part;
  part  = fmaxf(ax.x + bx.x + g0.x, 0.f) * w0.x;
  part  = fmaf(fmaxf(ax.y + bx.y + g0.y, 0.f), w0.y, part);
  part  = fmaf(fmaxf(ay.x + by.x + g0.z, 0.f), w0.z, part);
  part  = fmaf(fmaxf(ay.y + by.y + g0.w, 0.f), w0.w, part);
  part  = fmaf(fmaxf(az.x + bz.x + g1.x, 0.f), w1.x, part);
  part  = fmaf(fmaxf(az.y + bz.y + g1.y, 0.f), w1.y, part);
  part  = fmaf(fmaxf(aw.x + bw.x + g1.z, 0.f), w1.z, part);
  part  = fmaf(fmaxf(aw.y + bw.y + g1.w, 0.f), w1.w, part);
#pragma unroll
  for (int mm = 1; mm < 16; mm <<= 1) part += __shfl_xor(part, mm, 64);
  if (l == 0) out[eid] = part + b2[0];
}

extern "C" void kernel_launch(void* const* d_in, const int* in_sizes, int n_in,
                              void* d_out, int out_size, void* d_ws, size_t ws_size,
                              hipStream_t stream){
  const float* x     = (const float*)d_in[0];
  const int*   ei    = (const int*)d_in[1];
  const int*   batch = (const int*)d_in[2];
  const int N = in_sizes[2];
  const int E = in_sizes[1] / 2;
  const int* src = ei;
  const int* dst = ei + E;

  float* ws = (float*)d_ws;
  const size_t N64 = (size_t)N * 64;
  // layout: [xl][xr][hE][buf5][hD] then ints (even-padded), then gc/G
  float* xl   = ws;
  float* xr   = ws + N64;
  float* hE   = ws + 2*N64;
  float* hD   = ws + 4*N64;
  unsigned* Au = (unsigned*)xl;      // N x 64 packed bf16x2
  unsigned* Bu = (unsigned*)xr;
  int* rowptr = (int*)(ws + 5*N64);  // N+2 (padded even)
  int* cursor = rowptr + (N + 2);    // N (also deg before scan)
  int* csr    = cursor + N;          // N + E
  float* gc   = (float*)(csr + (N + E)); // 8*64
  float* G    = gc + 512;                // 8*128

  // ---- CSR build (once, reused by all 3 layers) ----
  k_deg_init <<<(N+255)/256, 256, 0, stream>>>(cursor, N);
  k_deg_count<<<(E+255)/256, 256, 0, stream>>>(dst, cursor, E);
  k_scan     <<<1, 1024, 0, stream>>>(cursor, rowptr, N);
  k_selfloop <<<(N+255)/256, 256, 0, stream>>>(rowptr, cursor, csr, gc, N);
  k_scatter  <<<(E+255)/256, 256, 0, stream>>>(src, dst, cursor, csr, E);

  // ---- 3 GATv2 layers ----
  const float* h = x;
  float* hn = hD;
  for (int l = 0; l < 3; ++l){
    const float* Wl   = (const float*)d_in[3 + 9*l + 0];
    const float* bl   = (const float*)d_in[3 + 9*l + 1];
    const float* Wr   = (const float*)d_in[3 + 9*l + 2];
    const float* br   = (const float*)d_in[3 + 9*l + 3];
    const float* att  = (const float*)d_in[3 + 9*l + 4];
    const float* Wres = (const float*)d_in[3 + 9*l + 5];
    const float* bias = (const float*)d_in[3 + 9*l + 6];
    const float* lng  = (const float*)d_in[3 + 9*l + 7];
    const float* lnb  = (const float*)d_in[3 + 9*l + 8];
    if (l == 0)
      k_node_transform<32><<<(N+31)/32, 256, 0, stream>>>(h, Wl, bl, Wr, br, Wres, bias, xl, xr, hn, N);
    else
      k_node_transform<64><<<(N+31)/32, 256, 0, stream>>>(h, Wl, bl, Wr, br, Wres, bias, xl, xr, hn, N);
    k_gat_edge<<<(N+3)/4, 256, 0, stream>>>(xl, xr, att, lng, lnb, rowptr, csr, hn, N);
    h = hn;
    hn = (l == 0) ? hE : hD;   // L0->hD, L1->hE, L2->hD ; final node_repr = hD
  }

  // ---- readout ----
  const float* W1 = (const float*)d_in[30];
  const float* b1 = (const float*)d_in[31];
  const float* W2 = (const float*)d_in[32];
  const float* b2 = (const float*)d_in[33];

  int pool_waves = (N + 63) / 64;
  k_pool      <<<(pool_waves+3)/4, 256, 0, stream>>>(hD, batch, gc, N);
  k_graph_proj<<<1, 1024, 0, stream>>>(gc, W1, b1, G);
  k_node_proj <<<(N+31)/32, 256, 0, stream>>>(hD, W1, Au, Bu, N);
  k_edge_out  <<<((size_t)E*16 + 255)/256, 256, 0, stream>>>((const uint4*)Au, (const uint4*)Bu,
                                            G, src, dst, batch, W2, b2,
                                            (float*)d_out, E);
}

// Round 4
// 577.960 us; speedup vs baseline: 1.8629x; 1.1303x over previous
//
#include <hip/hip_runtime.h>
#include <math.h>

__device__ __forceinline__ float wave_sum(float v){
#pragma unroll
  for (int m = 1; m < 64; m <<= 1) v += __shfl_xor(v, m, 64);
  return v;
}

__device__ __forceinline__ unsigned pack_bf16(float a, float b){
  unsigned ua = __float_as_uint(a), ub = __float_as_uint(b);
  ua = (ua + 0x7FFFu + ((ua >> 16) & 1u)) >> 16;
  ub = (ub + 0x7FFFu + ((ub >> 16) & 1u)) >> 16;
  return ua | (ub << 16);
}
__device__ __forceinline__ float2 unpack_bf16(unsigned p){
  float2 r;
  r.x = __uint_as_float(p << 16);
  r.y = __uint_as_float(p & 0xFFFF0000u);
  return r;
}

// ---------------- CSR build (dst-major, self-loop first per node) ----------------
__global__ void k_deg_init(int* __restrict__ deg, int n){
  int i = blockIdx.x*blockDim.x + threadIdx.x;
  if (i < n) deg[i] = 1;          // self loop
}

__global__ void k_deg_count(const int* __restrict__ dst, int* __restrict__ deg, int e){
  int i = blockIdx.x*blockDim.x + threadIdx.x;
  if (i < e) atomicAdd(&deg[dst[i]], 1);
}

// ---- 3-phase parallel exclusive scan: deg[n] -> rowptr[n+1] ----
__global__ void k_scan_a(const int* __restrict__ deg, int* __restrict__ rowptr,
                         int* __restrict__ bsum, int n){
  __shared__ int sm[256];
  int i = blockIdx.x*256 + threadIdx.x;
  int v = (i < n) ? deg[i] : 0;
  sm[threadIdx.x] = v; __syncthreads();
#pragma unroll
  for (int off = 1; off < 256; off <<= 1){
    int t = (threadIdx.x >= off) ? sm[threadIdx.x - off] : 0;
    __syncthreads();
    sm[threadIdx.x] += t;
    __syncthreads();
  }
  if (i < n) rowptr[i] = sm[threadIdx.x] - v;   // exclusive within block
  if (threadIdx.x == 255) bsum[blockIdx.x] = sm[255];
}

__global__ void k_scan_b(int* __restrict__ bsum, int* __restrict__ rowptr, int nb, int n){
  __shared__ int sm[256];
  int t = threadIdx.x;
  int v = (t < nb) ? bsum[t] : 0;
  sm[t] = v; __syncthreads();
#pragma unroll
  for (int off = 1; off < 256; off <<= 1){
    int x = (t >= off) ? sm[t - off] : 0;
    __syncthreads();
    sm[t] += x;
    __syncthreads();
  }
  if (t < nb) bsum[t] = sm[t] - v;              // exclusive block offsets
  if (t == 255) rowptr[n] = sm[255];            // total
}

__global__ void k_scan_c(int* __restrict__ rowptr, const int* __restrict__ bsum, int n){
  int i = blockIdx.x*256 + threadIdx.x;
  if (i < n) rowptr[i] += bsum[blockIdx.x];
}

__global__ void k_selfloop(const int* __restrict__ rowptr, int* __restrict__ cursor,
                           int* __restrict__ csr, float* __restrict__ gc, int n){
  int i = blockIdx.x*blockDim.x + threadIdx.x;
  if (i < n){
    int r = rowptr[i];
    csr[r] = i;                   // self loop entry
    cursor[i] = r + 1;
  }
  if (i < 512) gc[i] = 0.f;       // zero the pooling accumulator
}

__global__ void k_scatter(const int* __restrict__ src, const int* __restrict__ dst,
                          int* __restrict__ cursor, int* __restrict__ csr, int e){
  int i = blockIdx.x*blockDim.x + threadIdx.x;
  if (i < e){
    int pos = atomicAdd(&cursor[dst[i]], 1);
    csr[pos] = src[i];
  }
}

// ------- per-layer node transforms: xl, xr, residual(+bias); 8 nodes per wave -------
template<int K>
__global__ void k_node_transform(const float* __restrict__ h,
                                 const float* __restrict__ Wl, const float* __restrict__ bl,
                                 const float* __restrict__ Wr, const float* __restrict__ br,
                                 const float* __restrict__ Wres, const float* __restrict__ bias,
                                 float* __restrict__ xl, float* __restrict__ xr,
                                 float* __restrict__ res, int n){
  int wq   = (blockIdx.x*blockDim.x + threadIdx.x) >> 6;
  int lane = threadIdx.x & 63;
  int n0 = wq * 8;
  if (n0 >= n) return;
  float hv[8];
#pragma unroll
  for (int j = 0; j < 8; ++j){
    int node = min(n0 + j, n - 1);
    hv[j] = (lane < K) ? h[(size_t)node*K + lane] : 0.f;
  }
  float aL[8], aR[8], aS[8];
  float blv = bl[lane], brv = br[lane], bsv = bias[lane];
#pragma unroll
  for (int j = 0; j < 8; ++j){ aL[j] = blv; aR[j] = brv; aS[j] = bsv; }
#pragma unroll 4
  for (int k = 0; k < K; ++k){
    float wl = Wl[k*64+lane], wr = Wr[k*64+lane], wsv = Wres[k*64+lane];
#pragma unroll
    for (int j = 0; j < 8; ++j){
      float hk = __shfl(hv[j], k, 64);
      aL[j] = fmaf(hk, wl,  aL[j]);
      aR[j] = fmaf(hk, wr,  aR[j]);
      aS[j] = fmaf(hk, wsv, aS[j]);
    }
  }
#pragma unroll
  for (int j = 0; j < 8; ++j){
    int node = n0 + j;
    if (node < n){
      size_t o = (size_t)node*64 + lane;
      xl[o] = aL[j]; xr[o] = aR[j]; res[o] = aS[j];
    }
  }
}

// --- fused: edge softmax (online, 4 edges in flight, pipelined gathers) + LN + relu ---
__global__ void k_gat_edge(const float* __restrict__ xl, const float* __restrict__ xr,
                           const float* __restrict__ att,
                           const float* __restrict__ lng, const float* __restrict__ lnb,
                           const int* __restrict__ rowptr, const int* __restrict__ csr,
                           float* __restrict__ hio /* in: residual, out: h_next */, int n){
  int node = (blockIdx.x*blockDim.x + threadIdx.x) >> 6;
  int lane = threadIdx.x & 63;
  if (node >= n) return;
  int sub = lane >> 4;          // edge slot (0..3)
  int l   = lane & 15;          // channels 4l .. 4l+3
  size_t base = (size_t)node*64 + 4*l;
  float4 xrv  = *(const float4*)&xr[base];
  float4 attv = *(const float4*)&att[4*l];
  int p0 = rowptr[node], p1 = rowptr[node+1];
  int deg = p1 - p0;            // >= 1 (self loop)
  int sreg = csr[p0 + min(lane, deg-1)];   // cache first 64 neighbor ids in regs
  int rounds = (deg + 3) >> 2;
  float m = -1e30f, dsum = 0.f;
  float a0=0.f, a1=0.f, a2=0.f, a3=0.f;
  // stage 0 prefetch
  int e = sub;
  bool vcur = e < deg;
  int scur = __shfl(sreg, vcur ? e : 0, 64);
  float4 xcur = *(const float4*)&xl[(size_t)scur*64 + 4*l];
  for (int r = 0; r < rounds; ++r){
    // prefetch next round's rows (independent of this round's compute)
    int en = 4*(r+1) + sub;
    bool vn = en < deg;
    int sn;
    if (en < 64) sn = __shfl(sreg, vn ? en : 0, 64);
    else         sn = csr[p0 + (vn ? en : 0)];
    float4 xnxt = xcur;
    if (r + 1 < rounds) xnxt = *(const float4*)&xl[(size_t)sn*64 + 4*l];
    // compute current
    float vx = xcur.x + xrv.x, vy = xcur.y + xrv.y;
    float vz = xcur.z + xrv.z, vw = xcur.w + xrv.w;
    vx = vx > 0.f ? vx : 0.2f*vx;  vy = vy > 0.f ? vy : 0.2f*vy;
    vz = vz > 0.f ? vz : 0.2f*vz;  vw = vw > 0.f ? vw : 0.2f*vw;
    float partial = fmaf(vx, attv.x, fmaf(vy, attv.y, fmaf(vz, attv.z, vw*attv.w)));
#pragma unroll
    for (int mm = 1; mm < 16; mm <<= 1) partial += __shfl_xor(partial, mm, 64);
    float logit = vcur ? partial : -3e30f;
    float nm = fmaxf(m, logit);
    float sc = __expf(m - nm);
    float w  = __expf(logit - nm);
    dsum = fmaf(dsum, sc, w);
    a0 = fmaf(a0, sc, w*xcur.x);
    a1 = fmaf(a1, sc, w*xcur.y);
    a2 = fmaf(a2, sc, w*xcur.z);
    a3 = fmaf(a3, sc, w*xcur.w);
    m = nm;
    xcur = xnxt; vcur = vn;
  }
  // merge the 4 sub-groups' online-softmax states (xor 16, then xor 32)
#pragma unroll
  for (int off = 16; off < 64; off <<= 1){
    float mo = __shfl_xor(m, off, 64);
    float M  = fmaxf(m, mo);
    float sc = __expf(m - M);
    dsum *= sc; a0 *= sc; a1 *= sc; a2 *= sc; a3 *= sc;
    m = M;
    dsum += __shfl_xor(dsum, off, 64);
    a0 += __shfl_xor(a0, off, 64);
    a1 += __shfl_xor(a1, off, 64);
    a2 += __shfl_xor(a2, off, 64);
    a3 += __shfl_xor(a3, off, 64);
  }
  float4 resv = *(const float4*)&hio[base];
  float inv = 1.f / dsum;
  float ox = fmaf(a0, inv, resv.x);
  float oy = fmaf(a1, inv, resv.y);
  float oz = fmaf(a2, inv, resv.z);
  float ow = fmaf(a3, inv, resv.w);
  // layernorm over 64 channels; each channel appears 4x across the wave
  float mean = wave_sum(ox + oy + oz + ow) * (1.f/256.f);
  float dx = ox - mean, dy = oy - mean, dz = oz - mean, dw = ow - mean;
  float var = wave_sum(fmaf(dx,dx, fmaf(dy,dy, fmaf(dz,dz, dw*dw)))) * (1.f/256.f);
  float rstd = rsqrtf(var + 1e-5f);
  if (sub == 0){
    float4 lg = *(const float4*)&lng[4*l];
    float4 lb = *(const float4*)&lnb[4*l];
    float4 out;
    out.x = fmaxf(fmaf(dx*rstd, lg.x, lb.x), 0.f);
    out.y = fmaxf(fmaf(dy*rstd, lg.y, lb.y), 0.f);
    out.z = fmaxf(fmaf(dz*rstd, lg.z, lb.z), 0.f);
    out.w = fmaxf(fmaf(dw*rstd, lg.w, lb.w), 0.f);
    *(float4*)&hio[base] = out;
  }
}

// ---------------- global add pool (batch is sorted) ----------------
__global__ void k_pool(const float* __restrict__ h, const int* __restrict__ batch,
                       float* __restrict__ gc, int n){
  int wid  = (blockIdx.x*blockDim.x + threadIdx.x) >> 6;
  int lane = threadIdx.x & 63;
  int n0 = wid*64;
  if (n0 >= n) return;
  int n1 = min(n0+64, n);
  int curg = batch[n0];
  float s = 0.f;
  for (int i = n0; i < n1; ++i){
    int g = batch[i];
    if (g != curg){ atomicAdd(&gc[curg*64+lane], s); s = 0.f; curg = g; }
    s += h[(size_t)i*64 + lane];
  }
  atomicAdd(&gc[curg*64+lane], s);
}

// ---------------- G[g] = gc[g] @ W1c + b1 ----------------
__global__ void k_graph_proj(const float* __restrict__ gc, const float* __restrict__ W1,
                             const float* __restrict__ b1, float* __restrict__ G){
  int g = threadIdx.x >> 7;       // 8 graphs x 128 cols = 1024 threads
  int j = threadIdx.x & 127;
  float a = b1[j];
#pragma unroll 8
  for (int k = 0; k < 64; ++k) a = fmaf(gc[g*64+k], W1[(128+k)*128 + j], a);
  G[g*128 + j] = a;
}

// -------- A = nr @ W1a ; B = nr @ W1b (bf16 packed, 8 nodes per wave) --------
// lane holds output columns (2*lane, 2*lane+1)
__global__ void k_node_proj(const float* __restrict__ nr, const float* __restrict__ W1,
                            unsigned* __restrict__ Au, unsigned* __restrict__ Bu, int n){
  int wq   = (blockIdx.x*blockDim.x + threadIdx.x) >> 6;
  int lane = threadIdx.x & 63;
  int n0 = wq * 8;
  if (n0 >= n) return;
  float hv[8];
#pragma unroll
  for (int j = 0; j < 8; ++j){
    int node = min(n0 + j, n - 1);
    hv[j] = nr[(size_t)node*64 + lane];
  }
  float a0[8], a1[8], b0[8], b1v[8];
#pragma unroll
  for (int j = 0; j < 8; ++j){ a0[j]=0.f; a1[j]=0.f; b0[j]=0.f; b1v[j]=0.f; }
#pragma unroll 4
  for (int k = 0; k < 64; ++k){
    float2 wa = *(const float2*)&W1[k*128 + 2*lane];
    float2 wb = *(const float2*)&W1[(64+k)*128 + 2*lane];
#pragma unroll
    for (int j = 0; j < 8; ++j){
      float hk = __shfl(hv[j], k, 64);
      a0[j]  = fmaf(hk, wa.x, a0[j]);
      a1[j]  = fmaf(hk, wa.y, a1[j]);
      b0[j]  = fmaf(hk, wb.x, b0[j]);
      b1v[j] = fmaf(hk, wb.y, b1v[j]);
    }
  }
#pragma unroll
  for (int j = 0; j < 8; ++j){
    int node = n0 + j;
    if (node < n){
      size_t o = (size_t)node*64 + lane;
      Au[o] = pack_bf16(a0[j], a1[j]);
      Bu[o] = pack_bf16(b0[j], b1v[j]);
    }
  }
}

// -- final per-edge MLP: relu(A[s]+B[d]+G[g]) . W2 + b2 ; 4 edges/wave, 16 lanes/edge --
__global__ void k_edge_out(const uint4* __restrict__ Au4, const uint4* __restrict__ Bu4,
                           const float* __restrict__ G,
                           const int* __restrict__ src, const int* __restrict__ dst,
                           const int* __restrict__ batch,
                           const float* __restrict__ W2, const float* __restrict__ b2,
                           float* __restrict__ out, int e){
  int t = blockIdx.x*blockDim.x + threadIdx.x;
  int eid = t >> 4;
  int l   = t & 15;             // channels 8l .. 8l+7
  if (eid >= e) return;
  int s = src[eid], d = dst[eid];
  int g = batch[s];
  uint4 a = Au4[(size_t)s*16 + l];
  uint4 b = Bu4[(size_t)d*16 + l];
  const float* Gp = &G[g*128 + 8*l];
  float4 g0 = *(const float4*)Gp;
  float4 g1 = *(const float4*)(Gp + 4);
  float4 w0 = *(const float4*)&W2[8*l];
  float4 w1 = *(const float4*)&W2[8*l + 4];
  float2 ax = unpack_bf16(a.x), bx = unpack_bf16(b.x);
  float2 ay = unpack_bf16(a.y), by = unpack_bf16(b.y);
  float2 az = unpack_bf16(a.z), bz = unpack_bf16(b.z);
  float2 aw = unpack_bf16(a.w), bw = unpack_bf16(b.w);
  float part;
  part  = fmaxf(ax.x + bx.x + g0.x, 0.f) * w0.x;
  part  = fmaf(fmaxf(ax.y + bx.y + g0.y, 0.f), w0.y, part);
  part  = fmaf(fmaxf(ay.x + by.x + g0.z, 0.f), w0.z, part);
  part  = fmaf(fmaxf(ay.y + by.y + g0.w, 0.f), w0.w, part);
  part  = fmaf(fmaxf(az.x + bz.x + g1.x, 0.f), w1.x, part);
  part  = fmaf(fmaxf(az.y + bz.y + g1.y, 0.f), w1.y, part);
  part  = fmaf(fmaxf(aw.x + bw.x + g1.z, 0.f), w1.z, part);
  part  = fmaf(fmaxf(aw.y + bw.y + g1.w, 0.f), w1.w, part);
#pragma unroll
  for (int mm = 1; mm < 16; mm <<= 1) part += __shfl_xor(part, mm, 64);
  if (l == 0) out[eid] = part + b2[0];
}

extern "C" void kernel_launch(void* const* d_in, const int* in_sizes, int n_in,
                              void* d_out, int out_size, void* d_ws, size_t ws_size,
                              hipStream_t stream){
  const float* x     = (const float*)d_in[0];
  const int*   ei    = (const int*)d_in[1];
  const int*   batch = (const int*)d_in[2];
  const int N = in_sizes[2];
  const int E = in_sizes[1] / 2;
  const int* src = ei;
  const int* dst = ei + E;

  float* ws = (float*)d_ws;
  const size_t N64 = (size_t)N * 64;
  // layout: [xl][xr][hE][buf5][hD] then ints (even-padded), then gc/G/bsum
  float* xl   = ws;
  float* xr   = ws + N64;
  float* hE   = ws + 2*N64;
  float* hD   = ws + 4*N64;
  unsigned* Au = (unsigned*)xl;      // N x 64 packed bf16x2
  unsigned* Bu = (unsigned*)xr;
  int* rowptr = (int*)(ws + 5*N64);  // N+2 (padded even)
  int* cursor = rowptr + (N + 2);    // N (also deg before scan)
  int* csr    = cursor + N;          // N + E
  float* gc   = (float*)(csr + (N + E)); // 8*64
  float* G    = gc + 512;                // 8*128
  int* bsum   = (int*)(G + 1024);        // ceil(N/256) block sums

  const int NB = (N + 255) / 256;        // scan blocks (196 <= 256)

  // ---- CSR build (once, reused by all 3 layers) ----
  k_deg_init <<<(N+255)/256, 256, 0, stream>>>(cursor, N);
  k_deg_count<<<(E+255)/256, 256, 0, stream>>>(dst, cursor, E);
  k_scan_a   <<<NB, 256, 0, stream>>>(cursor, rowptr, bsum, N);
  k_scan_b   <<<1, 256, 0, stream>>>(bsum, rowptr, NB, N);
  k_scan_c   <<<NB, 256, 0, stream>>>(rowptr, bsum, N);
  k_selfloop <<<(N+255)/256, 256, 0, stream>>>(rowptr, cursor, csr, gc, N);
  k_scatter  <<<(E+255)/256, 256, 0, stream>>>(src, dst, cursor, csr, E);

  // ---- 3 GATv2 layers ----
  const float* h = x;
  float* hn = hD;
  for (int l = 0; l < 3; ++l){
    const float* Wl   = (const float*)d_in[3 + 9*l + 0];
    const float* bl   = (const float*)d_in[3 + 9*l + 1];
    const float* Wr   = (const float*)d_in[3 + 9*l + 2];
    const float* br   = (const float*)d_in[3 + 9*l + 3];
    const float* att  = (const float*)d_in[3 + 9*l + 4];
    const float* Wres = (const float*)d_in[3 + 9*l + 5];
    const float* bias = (const float*)d_in[3 + 9*l + 6];
    const float* lng  = (const float*)d_in[3 + 9*l + 7];
    const float* lnb  = (const float*)d_in[3 + 9*l + 8];
    if (l == 0)
      k_node_transform<32><<<(N+31)/32, 256, 0, stream>>>(h, Wl, bl, Wr, br, Wres, bias, xl, xr, hn, N);
    else
      k_node_transform<64><<<(N+31)/32, 256, 0, stream>>>(h, Wl, bl, Wr, br, Wres, bias, xl, xr, hn, N);
    k_gat_edge<<<(N+3)/4, 256, 0, stream>>>(xl, xr, att, lng, lnb, rowptr, csr, hn, N);
    h = hn;
    hn = (l == 0) ? hE : hD;   // L0->hD, L1->hE, L2->hD ; final node_repr = hD
  }

  // ---- readout ----
  const float* W1 = (const float*)d_in[30];
  const float* b1 = (const float*)d_in[31];
  const float* W2 = (const float*)d_in[32];
  const float* b2 = (const float*)d_in[33];

  int pool_waves = (N + 63) / 64;
  k_pool      <<<(pool_waves+3)/4, 256, 0, stream>>>(hD, batch, gc, N);
  k_graph_proj<<<1, 1024, 0, stream>>>(gc, W1, b1, G);
  k_node_proj <<<(N+31)/32, 256, 0, stream>>>(hD, W1, Au, Bu, N);
  k_edge_out  <<<((size_t)E*16 + 255)/256, 256, 0, stream>>>((const uint4*)Au, (const uint4*)Bu,
                                            G, src, dst, batch, W2, b2,
                                            (float*)d_out, E);
}

// Round 5
// 576.275 us; speedup vs baseline: 1.8684x; 1.0029x over previous
//
#include <hip/hip_runtime.h>
#include <math.h>

__device__ __forceinline__ float wave_sum(float v){
#pragma unroll
  for (int m = 1; m < 64; m <<= 1) v += __shfl_xor(v, m, 64);
  return v;
}

__device__ __forceinline__ unsigned short bf16_of(float a){
  unsigned ua = __float_as_uint(a);
  ua = (ua + 0x7FFFu + ((ua >> 16) & 1u)) >> 16;
  return (unsigned short)ua;
}
__device__ __forceinline__ unsigned pack_bf16(float a, float b){
  unsigned ua = __float_as_uint(a), ub = __float_as_uint(b);
  ua = (ua + 0x7FFFu + ((ua >> 16) & 1u)) >> 16;
  ub = (ub + 0x7FFFu + ((ub >> 16) & 1u)) >> 16;
  return ua | (ub << 16);
}
__device__ __forceinline__ float2 unpack_bf16(unsigned p){
  float2 r;
  r.x = __uint_as_float(p << 16);
  r.y = __uint_as_float(p & 0xFFFF0000u);
  return r;
}

// ---------------- CSR build (dst-major, self-loop first per node) ----------------
__global__ void k_deg_init(int* __restrict__ deg, int n){
  int i = blockIdx.x*blockDim.x + threadIdx.x;
  if (i < n) deg[i] = 1;          // self loop
}

__global__ void k_deg_count(const int* __restrict__ dst, int* __restrict__ deg, int e){
  int i = blockIdx.x*blockDim.x + threadIdx.x;
  if (i < e) atomicAdd(&deg[dst[i]], 1);
}

// ---- 3-phase parallel exclusive scan: deg[n] -> rowptr[n+1] ----
__global__ void k_scan_a(const int* __restrict__ deg, int* __restrict__ rowptr,
                         int* __restrict__ bsum, int n){
  __shared__ int sm[256];
  int i = blockIdx.x*256 + threadIdx.x;
  int v = (i < n) ? deg[i] : 0;
  sm[threadIdx.x] = v; __syncthreads();
#pragma unroll
  for (int off = 1; off < 256; off <<= 1){
    int t = (threadIdx.x >= off) ? sm[threadIdx.x - off] : 0;
    __syncthreads();
    sm[threadIdx.x] += t;
    __syncthreads();
  }
  if (i < n) rowptr[i] = sm[threadIdx.x] - v;   // exclusive within block
  if (threadIdx.x == 255) bsum[blockIdx.x] = sm[255];
}

__global__ void k_scan_b(int* __restrict__ bsum, int* __restrict__ rowptr, int nb, int n){
  __shared__ int sm[256];
  int t = threadIdx.x;
  int v = (t < nb) ? bsum[t] : 0;
  sm[t] = v; __syncthreads();
#pragma unroll
  for (int off = 1; off < 256; off <<= 1){
    int x = (t >= off) ? sm[t - off] : 0;
    __syncthreads();
    sm[t] += x;
    __syncthreads();
  }
  if (t < nb) bsum[t] = sm[t] - v;              // exclusive block offsets
  if (t == 255) rowptr[n] = sm[255];            // total
}

__global__ void k_scan_c(int* __restrict__ rowptr, const int* __restrict__ bsum, int n){
  int i = blockIdx.x*256 + threadIdx.x;
  if (i < n) rowptr[i] += bsum[blockIdx.x];
}

__global__ void k_selfloop(const int* __restrict__ rowptr, int* __restrict__ cursor,
                           int* __restrict__ csr, float* __restrict__ gc, int n){
  int i = blockIdx.x*blockDim.x + threadIdx.x;
  if (i < n){
    int r = rowptr[i];
    csr[r] = i;                   // self loop entry
    cursor[i] = r + 1;
  }
  if (i < 512) gc[i] = 0.f;       // zero the pooling accumulator
}

// scatter src into csr; also record original edge id at the self-loop-free position
__global__ void k_scatter(const int* __restrict__ src, const int* __restrict__ dst,
                          int* __restrict__ cursor, int* __restrict__ csr,
                          int* __restrict__ eidx, int e){
  int i = blockIdx.x*blockDim.x + threadIdx.x;
  if (i < e){
    int d = dst[i];
    int pos = atomicAdd(&cursor[d], 1);
    csr[pos] = src[i];
    eidx[pos - d - 1] = i;        // rowptr2[d] = rowptr[d]-d ; rank = pos-rowptr[d]-1
  }
}

// ------- per-layer node transforms: xl(bf16), xr, residual(+bias); 8 nodes/wave -------
template<int K>
__global__ void k_node_transform(const float* __restrict__ h,
                                 const float* __restrict__ Wl, const float* __restrict__ bl,
                                 const float* __restrict__ Wr, const float* __restrict__ br,
                                 const float* __restrict__ Wres, const float* __restrict__ bias,
                                 unsigned short* __restrict__ xlh, float* __restrict__ xr,
                                 float* __restrict__ res, int n){
  int wq   = (blockIdx.x*blockDim.x + threadIdx.x) >> 6;
  int lane = threadIdx.x & 63;
  int n0 = wq * 8;
  if (n0 >= n) return;
  float hv[8];
#pragma unroll
  for (int j = 0; j < 8; ++j){
    int node = min(n0 + j, n - 1);
    hv[j] = (lane < K) ? h[(size_t)node*K + lane] : 0.f;
  }
  float aL[8], aR[8], aS[8];
  float blv = bl[lane], brv = br[lane], bsv = bias[lane];
#pragma unroll
  for (int j = 0; j < 8; ++j){ aL[j] = blv; aR[j] = brv; aS[j] = bsv; }
#pragma unroll 4
  for (int k = 0; k < K; ++k){
    float wl = Wl[k*64+lane], wr = Wr[k*64+lane], wsv = Wres[k*64+lane];
#pragma unroll
    for (int j = 0; j < 8; ++j){
      float hk = __shfl(hv[j], k, 64);
      aL[j] = fmaf(hk, wl,  aL[j]);
      aR[j] = fmaf(hk, wr,  aR[j]);
      aS[j] = fmaf(hk, wsv, aS[j]);
    }
  }
#pragma unroll
  for (int j = 0; j < 8; ++j){
    int node = n0 + j;
    if (node < n){
      size_t o = (size_t)node*64 + lane;
      xlh[o] = bf16_of(aL[j]);
      xr[o] = aR[j]; res[o] = aS[j];
    }
  }
}

// --- fused: edge softmax (online, 4 edges in flight, bf16 xl gathers) + LN + relu ---
__global__ void k_gat_edge(const unsigned* __restrict__ xl_u, const float* __restrict__ xr,
                           const float* __restrict__ att,
                           const float* __restrict__ lng, const float* __restrict__ lnb,
                           const int* __restrict__ rowptr, const int* __restrict__ csr,
                           float* __restrict__ hio /* in: residual, out: h_next */, int n){
  int node = (blockIdx.x*blockDim.x + threadIdx.x) >> 6;
  int lane = threadIdx.x & 63;
  if (node >= n) return;
  int sub = lane >> 4;          // edge slot (0..3)
  int l   = lane & 15;          // channels 4l .. 4l+3
  size_t base = (size_t)node*64 + 4*l;
  float4 xrv  = *(const float4*)&xr[base];
  float4 attv = *(const float4*)&att[4*l];
  int p0 = rowptr[node], p1 = rowptr[node+1];
  int deg = p1 - p0;            // >= 1 (self loop)
  int sreg = csr[p0 + min(lane, deg-1)];   // cache first 64 neighbor ids in regs
  int rounds = (deg + 3) >> 2;
  float m = -1e30f, dsum = 0.f;
  float a0=0.f, a1=0.f, a2=0.f, a3=0.f;
  // stage 0 prefetch
  int e = sub;
  bool vcur = e < deg;
  int scur = __shfl(sreg, vcur ? e : 0, 64);
  uint2 xcur = *(const uint2*)&xl_u[(size_t)scur*32 + 2*l];
  for (int r = 0; r < rounds; ++r){
    // prefetch next round's rows (independent of this round's compute)
    int en = 4*(r+1) + sub;
    bool vn = en < deg;
    int sn;
    if (en < 64) sn = __shfl(sreg, vn ? en : 0, 64);
    else         sn = csr[p0 + (vn ? en : 0)];
    uint2 xnxt = xcur;
    if (r + 1 < rounds) xnxt = *(const uint2*)&xl_u[(size_t)sn*32 + 2*l];
    // compute current
    float2 p01 = unpack_bf16(xcur.x);
    float2 p23 = unpack_bf16(xcur.y);
    float vx = p01.x + xrv.x, vy = p01.y + xrv.y;
    float vz = p23.x + xrv.z, vw = p23.y + xrv.w;
    vx = vx > 0.f ? vx : 0.2f*vx;  vy = vy > 0.f ? vy : 0.2f*vy;
    vz = vz > 0.f ? vz : 0.2f*vz;  vw = vw > 0.f ? vw : 0.2f*vw;
    float partial = fmaf(vx, attv.x, fmaf(vy, attv.y, fmaf(vz, attv.z, vw*attv.w)));
#pragma unroll
    for (int mm = 1; mm < 16; mm <<= 1) partial += __shfl_xor(partial, mm, 64);
    float logit = vcur ? partial : -3e30f;
    float nm = fmaxf(m, logit);
    float sc = __expf(m - nm);
    float w  = __expf(logit - nm);
    dsum = fmaf(dsum, sc, w);
    a0 = fmaf(a0, sc, w*p01.x);
    a1 = fmaf(a1, sc, w*p01.y);
    a2 = fmaf(a2, sc, w*p23.x);
    a3 = fmaf(a3, sc, w*p23.y);
    m = nm;
    xcur = xnxt; vcur = vn;
  }
  // merge the 4 sub-groups' online-softmax states (xor 16, then xor 32)
#pragma unroll
  for (int off = 16; off < 64; off <<= 1){
    float mo = __shfl_xor(m, off, 64);
    float M  = fmaxf(m, mo);
    float sc = __expf(m - M);
    dsum *= sc; a0 *= sc; a1 *= sc; a2 *= sc; a3 *= sc;
    m = M;
    dsum += __shfl_xor(dsum, off, 64);
    a0 += __shfl_xor(a0, off, 64);
    a1 += __shfl_xor(a1, off, 64);
    a2 += __shfl_xor(a2, off, 64);
    a3 += __shfl_xor(a3, off, 64);
  }
  float4 resv = *(const float4*)&hio[base];
  float inv = 1.f / dsum;
  float ox = fmaf(a0, inv, resv.x);
  float oy = fmaf(a1, inv, resv.y);
  float oz = fmaf(a2, inv, resv.z);
  float ow = fmaf(a3, inv, resv.w);
  // layernorm over 64 channels; each channel appears 4x across the wave
  float mean = wave_sum(ox + oy + oz + ow) * (1.f/256.f);
  float dx = ox - mean, dy = oy - mean, dz = oz - mean, dw = ow - mean;
  float var = wave_sum(fmaf(dx,dx, fmaf(dy,dy, fmaf(dz,dz, dw*dw)))) * (1.f/256.f);
  float rstd = rsqrtf(var + 1e-5f);
  if (sub == 0){
    float4 lg = *(const float4*)&lng[4*l];
    float4 lb = *(const float4*)&lnb[4*l];
    float4 out;
    out.x = fmaxf(fmaf(dx*rstd, lg.x, lb.x), 0.f);
    out.y = fmaxf(fmaf(dy*rstd, lg.y, lb.y), 0.f);
    out.z = fmaxf(fmaf(dz*rstd, lg.z, lb.z), 0.f);
    out.w = fmaxf(fmaf(dw*rstd, lg.w, lb.w), 0.f);
    *(float4*)&hio[base] = out;
  }
}

// ---------------- global add pool (batch is sorted) ----------------
__global__ void k_pool(const float* __restrict__ h, const int* __restrict__ batch,
                       float* __restrict__ gc, int n){
  int wid  = (blockIdx.x*blockDim.x + threadIdx.x) >> 6;
  int lane = threadIdx.x & 63;
  int n0 = wid*64;
  if (n0 >= n) return;
  int n1 = min(n0+64, n);
  int curg = batch[n0];
  float s = 0.f;
  for (int i = n0; i < n1; ++i){
    int g = batch[i];
    if (g != curg){ atomicAdd(&gc[curg*64+lane], s); s = 0.f; curg = g; }
    s += h[(size_t)i*64 + lane];
  }
  atomicAdd(&gc[curg*64+lane], s);
}

// ---------------- G[g] = gc[g] @ W1c + b1 ----------------
__global__ void k_graph_proj(const float* __restrict__ gc, const float* __restrict__ W1,
                             const float* __restrict__ b1, float* __restrict__ G){
  int g = threadIdx.x >> 7;       // 8 graphs x 128 cols = 1024 threads
  int j = threadIdx.x & 127;
  float a = b1[j];
#pragma unroll 8
  for (int k = 0; k < 64; ++k) a = fmaf(gc[g*64+k], W1[(128+k)*128 + j], a);
  G[g*128 + j] = a;
}

// -------- A = nr @ W1a ; B = nr @ W1b (bf16 packed, 8 nodes per wave) --------
__global__ void k_node_proj(const float* __restrict__ nr, const float* __restrict__ W1,
                            unsigned* __restrict__ Au, unsigned* __restrict__ Bu, int n){
  int wq   = (blockIdx.x*blockDim.x + threadIdx.x) >> 6;
  int lane = threadIdx.x & 63;
  int n0 = wq * 8;
  if (n0 >= n) return;
  float hv[8];
#pragma unroll
  for (int j = 0; j < 8; ++j){
    int node = min(n0 + j, n - 1);
    hv[j] = nr[(size_t)node*64 + lane];
  }
  float a0[8], a1[8], b0[8], b1v[8];
#pragma unroll
  for (int j = 0; j < 8; ++j){ a0[j]=0.f; a1[j]=0.f; b0[j]=0.f; b1v[j]=0.f; }
#pragma unroll 4
  for (int k = 0; k < 64; ++k){
    float2 wa = *(const float2*)&W1[k*128 + 2*lane];
    float2 wb = *(const float2*)&W1[(64+k)*128 + 2*lane];
#pragma unroll
    for (int j = 0; j < 8; ++j){
      float hk = __shfl(hv[j], k, 64);
      a0[j]  = fmaf(hk, wa.x, a0[j]);
      a1[j]  = fmaf(hk, wa.y, a1[j]);
      b0[j]  = fmaf(hk, wb.x, b0[j]);
      b1v[j] = fmaf(hk, wb.y, b1v[j]);
    }
  }
#pragma unroll
  for (int j = 0; j < 8; ++j){
    int node = n0 + j;
    if (node < n){
      size_t o = (size_t)node*64 + lane;
      Au[o] = pack_bf16(a0[j], a1[j]);
      Bu[o] = pack_bf16(b0[j], b1v[j]);
    }
  }
}

// -- final per-edge MLP, dst-major: B[d] streamed once, A[s] gathered, out scattered --
// wave per node; 4 edge slots x 16 lanes (8 channels each)
__global__ void k_edge_out_csr(const uint4* __restrict__ Au4, const uint4* __restrict__ Bu4,
                               const float* __restrict__ G,
                               const int* __restrict__ rowptr, const int* __restrict__ csr,
                               const int* __restrict__ eidx, const int* __restrict__ batch,
                               const float* __restrict__ W2, const float* __restrict__ b2,
                               float* __restrict__ out, int n){
  int node = (blockIdx.x*blockDim.x + threadIdx.x) >> 6;
  int lane = threadIdx.x & 63;
  if (node >= n) return;
  int sub = lane >> 4;
  int l   = lane & 15;            // dwords 4l..4l+3 = channels 8l..8l+7
  int p0 = rowptr[node];
  int deg2 = rowptr[node+1] - p0 - 1;      // excludes self loop
  if (deg2 <= 0) return;
  uint4 b = Bu4[(size_t)node*16 + l];      // B[d], shared by all edges of this node
  float4 w0 = *(const float4*)&W2[8*l];
  float4 w1 = *(const float4*)&W2[8*l + 4];
  float b2v = b2[0];
  float2 bx = unpack_bf16(b.x), by = unpack_bf16(b.y);
  float2 bz = unpack_bf16(b.z), bw = unpack_bf16(b.w);
  int rounds = (deg2 + 3) >> 2;
  // stage 0 prefetch
  int e = sub;
  bool vcur = e < deg2;
  int scur = csr[p0 + 1 + (vcur ? e : 0)];
  int ecur = eidx[p0 - node + (vcur ? e : 0)];
  uint4 acur = Au4[(size_t)scur*16 + l];
  for (int r = 0; r < rounds; ++r){
    int en = 4*(r+1) + sub;
    bool vn = en < deg2;
    int sn = csr[p0 + 1 + (vn ? en : 0)];
    int en2 = eidx[p0 - node + (vn ? en : 0)];
    uint4 anxt = acur;
    if (r + 1 < rounds) anxt = Au4[(size_t)sn*16 + l];
    // compute current edge
    int g = batch[scur];
    const float* Gp = &G[g*128 + 8*l];
    float4 g0 = *(const float4*)Gp;
    float4 g1 = *(const float4*)(Gp + 4);
    float2 ax = unpack_bf16(acur.x), ay = unpack_bf16(acur.y);
    float2 az = unpack_bf16(acur.z), aw = unpack_bf16(acur.w);
    float part;
    part = fmaxf(ax.x + bx.x + g0.x, 0.f) * w0.x;
    part = fmaf(fmaxf(ax.y + bx.y + g0.y, 0.f), w0.y, part);
    part = fmaf(fmaxf(ay.x + by.x + g0.z, 0.f), w0.z, part);
    part = fmaf(fmaxf(ay.y + by.y + g0.w, 0.f), w0.w, part);
    part = fmaf(fmaxf(az.x + bz.x + g1.x, 0.f), w1.x, part);
    part = fmaf(fmaxf(az.y + bz.y + g1.y, 0.f), w1.y, part);
    part = fmaf(fmaxf(aw.x + bw.x + g1.z, 0.f), w1.z, part);
    part = fmaf(fmaxf(aw.y + bw.y + g1.w, 0.f), w1.w, part);
#pragma unroll
    for (int mm = 1; mm < 16; mm <<= 1) part += __shfl_xor(part, mm, 64);
    if (l == 0 && vcur) out[ecur] = part + b2v;
    acur = anxt; vcur = vn; scur = sn; ecur = en2;
  }
}

extern "C" void kernel_launch(void* const* d_in, const int* in_sizes, int n_in,
                              void* d_out, int out_size, void* d_ws, size_t ws_size,
                              hipStream_t stream){
  const float* x     = (const float*)d_in[0];
  const int*   ei    = (const int*)d_in[1];
  const int*   batch = (const int*)d_in[2];
  const int N = in_sizes[2];
  const int E = in_sizes[1] / 2;
  const int* src = ei;
  const int* dst = ei + E;

  unsigned* W = (unsigned*)d_ws;
  const size_t N32 = (size_t)N * 32;
  const size_t N64 = (size_t)N * 64;
  // dword layout: [xl bf16: N32][xr: N64][hE: N64][hD: N64] | ints | gc/G/bsum
  unsigned short* xlh = (unsigned short*)W;          // N x 64 bf16
  unsigned* xl_u = W;                                // same, read as uint2
  float* xr = (float*)(W + N32);
  float* hE = (float*)(W + N32 + N64);
  float* hD = (float*)(W + N32 + 2*N64);
  // readout aliases (xl/xr/hE dead by then; hD untouched)
  unsigned* Au = W;                                  // N x 64 dwords
  unsigned* Bu = W + N64;                            // N x 64 dwords (ends < hD)
  int* rowptr = (int*)(W + N32 + 3*N64);             // N+2
  int* cursor = rowptr + (N + 2);                    // N
  int* csr    = cursor + N;                          // N + E
  int* eidx   = csr + (N + E);                       // E
  float* gc   = (float*)(eidx + E);                  // 8*64
  float* G    = gc + 512;                            // 8*128
  int* bsum   = (int*)(G + 1024);                    // ceil(N/256)

  const int NB = (N + 255) / 256;

  // ---- CSR build (once, reused by all 3 layers + edge MLP) ----
  k_deg_init <<<(N+255)/256, 256, 0, stream>>>(cursor, N);
  k_deg_count<<<(E+255)/256, 256, 0, stream>>>(dst, cursor, E);
  k_scan_a   <<<NB, 256, 0, stream>>>(cursor, rowptr, bsum, N);
  k_scan_b   <<<1, 256, 0, stream>>>(bsum, rowptr, NB, N);
  k_scan_c   <<<NB, 256, 0, stream>>>(rowptr, bsum, N);
  k_selfloop <<<(N+255)/256, 256, 0, stream>>>(rowptr, cursor, csr, gc, N);
  k_scatter  <<<(E+255)/256, 256, 0, stream>>>(src, dst, cursor, csr, eidx, E);

  // ---- 3 GATv2 layers ----
  const float* h = x;
  float* hn = hD;
  for (int l = 0; l < 3; ++l){
    const float* Wl   = (const float*)d_in[3 + 9*l + 0];
    const float* bl   = (const float*)d_in[3 + 9*l + 1];
    const float* Wr   = (const float*)d_in[3 + 9*l + 2];
    const float* br   = (const float*)d_in[3 + 9*l + 3];
    const float* att  = (const float*)d_in[3 + 9*l + 4];
    const float* Wres = (const float*)d_in[3 + 9*l + 5];
    const float* bias = (const float*)d_in[3 + 9*l + 6];
    const float* lng  = (const float*)d_in[3 + 9*l + 7];
    const float* lnb  = (const float*)d_in[3 + 9*l + 8];
    if (l == 0)
      k_node_transform<32><<<(N+31)/32, 256, 0, stream>>>(h, Wl, bl, Wr, br, Wres, bias, xlh, xr, hn, N);
    else
      k_node_transform<64><<<(N+31)/32, 256, 0, stream>>>(h, Wl, bl, Wr, br, Wres, bias, xlh, xr, hn, N);
    k_gat_edge<<<(N+3)/4, 256, 0, stream>>>(xl_u, xr, att, lng, lnb, rowptr, csr, hn, N);
    h = hn;
    hn = (l == 0) ? hE : hD;   // L0->hD, L1->hE, L2->hD ; final node_repr = hD
  }

  // ---- readout ----
  const float* W1 = (const float*)d_in[30];
  const float* b1 = (const float*)d_in[31];
  const float* W2 = (const float*)d_in[32];
  const float* b2 = (const float*)d_in[33];

  int pool_waves = (N + 63) / 64;
  k_pool      <<<(pool_waves+3)/4, 256, 0, stream>>>(hD, batch, gc, N);
  k_graph_proj<<<1, 1024, 0, stream>>>(gc, W1, b1, G);
  k_node_proj <<<(N+31)/32, 256, 0, stream>>>(hD, W1, Au, Bu, N);
  k_edge_out_csr<<<(N+3)/4, 256, 0, stream>>>((const uint4*)Au, (const uint4*)Bu, G,
                                              rowptr, csr, eidx, batch, W2, b2,
                                              (float*)d_out, N);
}